// Round 1
// baseline (2188.132 us; speedup 1.0000x reference)
//
#include <hip/hip_runtime.h>
#include <math.h>

// ---- problem constants ----
#define B_TOT   2048
#define H_STEPS 64
#define A_DIM   32
#define S_DIM   32
#define D_DIM   200
#define OUT_FEAT 296
#define BT      2            // batch rows per block -> grid 1024 = 4 blocks/CU (16 waves/CU)

// ---- workspace layout (dword offsets): f16-pair-packed weights ----
// RUN4 uint4[66*200] : per k-group g (k=4g..4g+3): (Rpk(2g),Rpk(2g+1),Upk(2g),Upk(2g+1))
// N2   uint2[66*200] : (Npk(2g),Npk(2g+1))
// W1P  uint2[50*200], W2P uint2[50*200], MS2 uint2[50*64]
#define OFF_RUN4 0
#define OFF_N2   52800
#define OFF_W1   79200
#define OFF_W2   99200
#define OFF_MS   119200
#define WS_DW    125600

typedef _Float16 half2_t __attribute__((ext_vector_type(2)));

__device__ __forceinline__ unsigned pack_h2(float a, float b) {
    union { _Float16 h[2]; unsigned u; } v;
    v.h[0] = (_Float16)a; v.h[1] = (_Float16)b;
    return v.u;
}
__device__ __forceinline__ unsigned f2u16(float x) {
    union { _Float16 h[2]; unsigned u; } v;
    v.u = 0; v.h[0] = (_Float16)x;
    return v.u;
}
__device__ __forceinline__ float dot2f(unsigned w, unsigned x, float c) {
    union { unsigned u; half2_t h; } a, b;
    a.u = w; b.u = x;
#if __has_builtin(__builtin_amdgcn_fdot2)
    return __builtin_amdgcn_fdot2(a.h, b.h, c, false);
#else
    return c + (float)a.h[0] * (float)b.h[0] + (float)a.h[1] * (float)b.h[1];
#endif
}
__device__ __forceinline__ float fast_rcp(float x) { return __builtin_amdgcn_rcpf(x); }
__device__ __forceinline__ float sigmoid_f(float x) {
    return fast_rcp(1.0f + __expf(-x));
}
__device__ __forceinline__ float tanh_f(float x) {
    // 1 - 2/(1+e^{2x}); safe at both extremes
    return 1.0f - 2.0f * fast_rcp(1.0f + __expf(2.0f * x));
}
// combined-k fetch: k<64 -> W_ih col, else W_hh col (row = gate-row index)
__device__ __forceinline__ float gw(const float* Wih, const float* Whh, int row, int k) {
    return (k < 64) ? Wih[row * 64 + k] : Whh[row * 200 + (k - 64)];
}

__global__ void pack_weights(const float* __restrict__ Wih, const float* __restrict__ Whh,
                             const float* __restrict__ W1, const float* __restrict__ W2,
                             const float* __restrict__ Wm, const float* __restrict__ Ws,
                             unsigned* __restrict__ ws)
{
    int i = blockIdx.x * 256 + threadIdx.x;
    if (i >= WS_DW) return;
    if (i < OFF_N2) {                         // RUN4
        int e = i >> 2, c = i & 3;
        int g = e / 200, t = e % 200;
        int kp = 2 * g + (c & 1);
        int row = (c >> 1) ? (200 + t) : t;   // c<2: r-gate rows, c>=2: u-gate rows
        ws[i] = pack_h2(gw(Wih, Whh, row, 2 * kp), gw(Wih, Whh, row, 2 * kp + 1));
    } else if (i < OFF_W1) {                  // N2
        int j = i - OFF_N2, e = j >> 1, c = j & 1;
        int g = e / 200, t = e % 200, kp = 2 * g + c, row = 400 + t;
        ws[i] = pack_h2(gw(Wih, Whh, row, 2 * kp), gw(Wih, Whh, row, 2 * kp + 1));
    } else if (i < OFF_W2) {                  // W1P
        int j = i - OFF_W1, e = j >> 1, c = j & 1;
        int g = e / 200, t = e % 200, kp = 2 * g + c;
        ws[i] = pack_h2(W1[t * 200 + 2 * kp], W1[t * 200 + 2 * kp + 1]);
    } else if (i < OFF_MS) {                  // W2P
        int j = i - OFF_W2, e = j >> 1, c = j & 1;
        int g = e / 200, t = e % 200, kp = 2 * g + c;
        ws[i] = pack_h2(W2[t * 200 + 2 * kp], W2[t * 200 + 2 * kp + 1]);
    } else {                                  // MS2
        int j = i - OFF_MS, e = j >> 1, c = j & 1;
        int g = e / 64, o = e % 64, kp = 2 * g + c;
        const float* src = (o < 32) ? (Wm + o * 200) : (Ws + (o - 32) * 200);
        ws[i] = pack_h2(src[2 * kp], src[2 * kp + 1]);
    }
}

// pack 2 fp32 (one per batch) into half2 pairs with lane t^1; even lanes store b64
__device__ __forceinline__ void pack_store2(unsigned* dst, int pairidx, int odd,
                                            float v0, float v1) {
    unsigned a0 = f2u16(v0), a1 = f2u16(v1);
    unsigned p0 = (unsigned)__shfl_xor((int)a0, 1, 64);
    unsigned p1 = (unsigned)__shfl_xor((int)a1, 1, 64);
    if (!odd) {
        uint2 w;
        w.x = a0 | (p0 << 16); w.y = a1 | (p1 << 16);
        ((uint2*)dst)[pairidx] = w;
    }
}

__global__ __launch_bounds__(256) void rssm_rollout(
    const float* __restrict__ h0, const float* __restrict__ z0,
    const float* __restrict__ actions, const float* __restrict__ eps,
    const float* __restrict__ b_ih, const float* __restrict__ b_hh,
    const float* __restrict__ b1, const float* __restrict__ b2,
    const float* __restrict__ bm, const float* __restrict__ bs,
    const unsigned* __restrict__ wsu, float* __restrict__ out)
{
    __shared__ __align__(16) unsigned azpk[32 * BT];      // z pairs (kp0-15), a pairs (kp16-31)
    __shared__ __align__(16) unsigned hpk[2][100 * BT];   // packed h, double-buffered
    __shared__ __align__(16) float    hf[2][200 * BT];    // fp32 h (leak term), double-buffered
    __shared__ __align__(16) unsigned f1pk[100 * BT];
    __shared__ __align__(16) unsigned f2pk[100 * BT];

    const int t  = threadIdx.x;
    const int b0 = blockIdx.x * BT;

    const uint4* RUN4 = (const uint4*)(wsu + OFF_RUN4);
    const uint2* N2w  = (const uint2*)(wsu + OFF_N2);
    const uint2* W1w  = (const uint2*)(wsu + OFF_W1);
    const uint2* W2w  = (const uint2*)(wsu + OFF_W2);
    const uint2* MSw  = (const uint2*)(wsu + OFF_MS);

    // hoisted biases
    float brz = 0.f, buz = 0.f, bin = 0.f, bhn = 0.f, b1t = 0.f, b2t = 0.f, bms = 0.f;
    if (t < 200) {
        brz = b_ih[t] + b_hh[t];
        buz = b_ih[200 + t] + b_hh[200 + t];
        bin = b_ih[400 + t];
        bhn = b_hh[400 + t];
        b1t = b1[t];
        b2t = b2[t];
    }
    if (t < 64) bms = (t < 32) ? bm[t] : bs[t - 32];

    // ---- init state ----
    if (t < 200) {
        float hv[BT];
        #pragma unroll
        for (int b = 0; b < BT; ++b) hv[b] = h0[(b0 + b) * 200 + t];
        ((float2*)hf[0])[t] = make_float2(hv[0], hv[1]);
        pack_store2(hpk[0], t >> 1, t & 1, hv[0], hv[1]);
    }
    if (t < 32) {
        float zv[BT];
        #pragma unroll
        for (int b = 0; b < BT; ++b) zv[b] = z0[(b0 + b) * 32 + t];
        pack_store2(azpk, t >> 1, t & 1, zv[0], zv[1]);
    }
    // prefetch step-0 actions / eps
    float areg = 0.f;
    float ereg[BT] = {0.f, 0.f};
    if (t < 32 * BT) {
        int b = t >> 5, j = t & 31;
        areg = actions[((b0 + b) * H_STEPS + 0) * 32 + j];
    }
    if (t < 32) {
        #pragma unroll
        for (int b = 0; b < BT; ++b) ereg[b] = eps[((b0 + b) * H_STEPS + 0) * 32 + t];
    }

    for (int step = 0; step < H_STEPS; ++step) {
        const int cur = step & 1, nxt = cur ^ 1;

        // write prefetched actions into azpk a-part
        if (t < 32 * BT) {
            int b = t >> 5, j = t & 31;
            unsigned lo = f2u16(areg);
            unsigned hi = (unsigned)__shfl_xor((int)lo, 1, 64);
            if (!(j & 1)) azpk[(16 + (j >> 1)) * BT + b] = lo | (hi << 16);
        }
        __syncthreads();   // B1: azpk (z from prev sample, a), hpk[cur], hf[cur] ready

        const int sp = (step + 1 < H_STEPS) ? step + 1 : step;
        if (t < 32 * BT) {     // prefetch next actions (latency hides under GRU)
            int b = t >> 5, j = t & 31;
            areg = actions[((b0 + b) * H_STEPS + sp) * 32 + j];
        }

        // ---- GRU: thread t = feature t, dot over combined k via v_dot2_f32_f16 ----
        if (t < 200) {
            float ar[BT]  = {0.f, 0.f};
            float au[BT]  = {0.f, 0.f};
            float anx[BT] = {0.f, 0.f};
            float anh[BT] = {0.f, 0.f};
            const uint2* az2 = (const uint2*)azpk;
            const uint2* hc2 = (const uint2*)hpk[cur];

            #pragma unroll 4
            for (int g = 0; g < 16; ++g) {       // k = 0..63 (z,a)
                uint4 w  = RUN4[g * 200 + t];
                uint2 wn = N2w[g * 200 + t];
                uint2 xa = az2[2 * g], xb = az2[2 * g + 1];
                const unsigned* pa = (const unsigned*)&xa;
                const unsigned* pb = (const unsigned*)&xb;
                #pragma unroll
                for (int b = 0; b < BT; ++b) {
                    ar[b]  = dot2f(w.x,  pa[b], ar[b]);  ar[b]  = dot2f(w.y,  pb[b], ar[b]);
                    au[b]  = dot2f(w.z,  pa[b], au[b]);  au[b]  = dot2f(w.w,  pb[b], au[b]);
                    anx[b] = dot2f(wn.x, pa[b], anx[b]); anx[b] = dot2f(wn.y, pb[b], anx[b]);
                }
            }
            #pragma unroll 2
            for (int g = 16; g < 66; ++g) {      // k = 64..263 (h)
                uint4 w  = RUN4[g * 200 + t];
                uint2 wn = N2w[g * 200 + t];
                int lk = 2 * (g - 16);
                uint2 xa = hc2[lk], xb = hc2[lk + 1];
                const unsigned* pa = (const unsigned*)&xa;
                const unsigned* pb = (const unsigned*)&xb;
                #pragma unroll
                for (int b = 0; b < BT; ++b) {
                    ar[b]  = dot2f(w.x,  pa[b], ar[b]);  ar[b]  = dot2f(w.y,  pb[b], ar[b]);
                    au[b]  = dot2f(w.z,  pa[b], au[b]);  au[b]  = dot2f(w.w,  pb[b], au[b]);
                    anh[b] = dot2f(wn.x, pa[b], anh[b]); anh[b] = dot2f(wn.y, pb[b], anh[b]);
                }
            }
            const float2 ho2 = ((const float2*)hf[cur])[t];
            const float ho[BT] = {ho2.x, ho2.y};
            float hn[BT];
            const int obase = (b0 * H_STEPS + step) * OUT_FEAT + t;
            #pragma unroll
            for (int b = 0; b < BT; ++b) {
                float r = sigmoid_f(ar[b] + brz);
                float u = sigmoid_f(au[b] + buz);
                float n = tanh_f(anx[b] + bin + r * (anh[b] + bhn));
                hn[b] = (1.0f - u) * n + u * ho[b];
                out[obase + b * (H_STEPS * OUT_FEAT)] = hn[b];
            }
            ((float2*)hf[nxt])[t] = make_float2(hn[0], hn[1]);
            pack_store2(hpk[nxt], t >> 1, t & 1, hn[0], hn[1]);
        }
        __syncthreads();   // B2: h_new ready

        // ---- f1 = elu(h_new @ W1^T + b1) ----
        if (t < 200) {
            float acc[BT] = {0.f, 0.f};
            const uint2* hv2 = (const uint2*)hpk[nxt];
            #pragma unroll 2
            for (int g = 0; g < 50; ++g) {
                uint2 w  = W1w[g * 200 + t];
                uint2 xa = hv2[2 * g], xb = hv2[2 * g + 1];
                const unsigned* pa = (const unsigned*)&xa;
                const unsigned* pb = (const unsigned*)&xb;
                #pragma unroll
                for (int b = 0; b < BT; ++b) {
                    acc[b] = dot2f(w.x, pa[b], acc[b]);
                    acc[b] = dot2f(w.y, pb[b], acc[b]);
                }
            }
            float r[BT];
            #pragma unroll
            for (int b = 0; b < BT; ++b) {
                float v = acc[b] + b1t;
                r[b] = (v > 0.f) ? v : (__expf(v) - 1.0f);
            }
            pack_store2(f1pk, t >> 1, t & 1, r[0], r[1]);
        }
        __syncthreads();   // B3: f1 ready

        // ---- f2 = elu(f1 @ W2^T + b2) ----
        if (t < 200) {
            float acc[BT] = {0.f, 0.f};
            const uint2* fv2 = (const uint2*)f1pk;
            #pragma unroll 2
            for (int g = 0; g < 50; ++g) {
                uint2 w  = W2w[g * 200 + t];
                uint2 xa = fv2[2 * g], xb = fv2[2 * g + 1];
                const unsigned* pa = (const unsigned*)&xa;
                const unsigned* pb = (const unsigned*)&xb;
                #pragma unroll
                for (int b = 0; b < BT; ++b) {
                    acc[b] = dot2f(w.x, pa[b], acc[b]);
                    acc[b] = dot2f(w.y, pb[b], acc[b]);
                }
            }
            float r[BT];
            #pragma unroll
            for (int b = 0; b < BT; ++b) {
                float v = acc[b] + b2t;
                r[b] = (v > 0.f) ? v : (__expf(v) - 1.0f);
            }
            pack_store2(f2pk, t >> 1, t & 1, r[0], r[1]);
        }
        __syncthreads();   // B4: f2 ready

        // ---- heads (wave 0): mean / std + shfl exchange + sample ----
        if (t < 64) {
            float acc[BT] = {0.f, 0.f};
            const uint2* fv2 = (const uint2*)f2pk;
            #pragma unroll 2
            for (int g = 0; g < 50; ++g) {
                uint2 w  = MSw[g * 64 + t];
                uint2 xa = fv2[2 * g], xb = fv2[2 * g + 1];
                const unsigned* pa = (const unsigned*)&xa;
                const unsigned* pb = (const unsigned*)&xb;
                #pragma unroll
                for (int b = 0; b < BT; ++b) {
                    acc[b] = dot2f(w.x, pa[b], acc[b]);
                    acc[b] = dot2f(w.y, pb[b], acc[b]);
                }
            }
            float v[BT];
            if (t < 32) {
                #pragma unroll
                for (int b = 0; b < BT; ++b) v[b] = acc[b] + bms;               // mean
            } else {
                #pragma unroll
                for (int b = 0; b < BT; ++b) {
                    float ls = acc[b] + bms;
                    ls = fminf(fmaxf(ls, -10.0f), 2.0f);
                    v[b] = __expf(ls);                                          // std
                }
            }
            float sv[BT];
            #pragma unroll
            for (int b = 0; b < BT; ++b) sv[b] = __shfl(v[b], (t & 31) + 32, 64);
            if (t < 32) {
                float zv[BT];
                #pragma unroll
                for (int b = 0; b < BT; ++b) {
                    float z = v[b] + sv[b] * ereg[b];
                    zv[b] = z;
                    int base = ((b0 + b) * H_STEPS + step) * OUT_FEAT;
                    out[base + 200 + t] = z;
                    out[base + 232 + t] = v[b];
                }
                pack_store2(azpk, t >> 1, t & 1, zv[0], zv[1]);
            } else {
                #pragma unroll
                for (int b = 0; b < BT; ++b) {
                    int base = ((b0 + b) * H_STEPS + step) * OUT_FEAT;
                    out[base + 264 + (t - 32)] = v[b];
                }
            }
        }
        // prefetch next eps
        if (t < 32) {
            #pragma unroll
            for (int b = 0; b < BT; ++b)
                ereg[b] = eps[((b0 + b) * H_STEPS + sp) * 32 + t];
        }
        // loop: B1 covers azpk z-writes and the a-part write at top
    }
}

extern "C" void kernel_launch(void* const* d_in, const int* in_sizes, int n_in,
                              void* d_out, int out_size, void* d_ws, size_t ws_size,
                              hipStream_t stream) {
    const float* h0      = (const float*)d_in[0];
    const float* z0      = (const float*)d_in[1];
    const float* actions = (const float*)d_in[2];
    const float* eps     = (const float*)d_in[3];
    const float* W_ih    = (const float*)d_in[4];
    const float* b_ih    = (const float*)d_in[5];
    const float* W_hh    = (const float*)d_in[6];
    const float* b_hh    = (const float*)d_in[7];
    const float* W1      = (const float*)d_in[8];
    const float* b1      = (const float*)d_in[9];
    const float* W2      = (const float*)d_in[10];
    const float* b2      = (const float*)d_in[11];
    const float* Wm      = (const float*)d_in[12];
    const float* bm      = (const float*)d_in[13];
    const float* Ws      = (const float*)d_in[14];
    const float* bs      = (const float*)d_in[15];

    unsigned* ws = (unsigned*)d_ws;
    float* out = (float*)d_out;

    hipLaunchKernelGGL(pack_weights, dim3((WS_DW + 255) / 256), dim3(256), 0, stream,
                       W_ih, W_hh, W1, W2, Wm, Ws, ws);

    hipLaunchKernelGGL(rssm_rollout, dim3(B_TOT / BT), dim3(256), 0, stream,
                       h0, z0, actions, eps, b_ih, b_hh, b1, b2, bm, bs, ws, out);
}

// Round 2
// 1048.406 us; speedup vs baseline: 2.0871x; 2.0871x over previous
//
#include <hip/hip_runtime.h>
#include <math.h>

// ---- problem constants ----
#define B_TOT    2048
#define H_STEPS  64
#define OUT_FEAT 296
#define BT       16           // batch rows per block -> grid 128, 1 block/CU

// ---- workspace layout (dword offsets), f16 MFMA B-fragments ----
// GRU: 13 j-tiles x 27 frag-groups (r:ks0-8, u:ks0-8, in:ks0-1, hn:ks2-8), 64 lanes x 16B
// W1 : 13 x 7, W2: 13 x 7, MS: 4 x 7
#define OFF_GRU 0
#define OFF_W1  89856        // 13*27*1024B /4
#define OFF_W2  113152       // +13*7*1024B/4
#define OFF_MS  136448
#define WS_DW   143616       // 574,464 bytes total

typedef _Float16 f16;
typedef _Float16 f16x8 __attribute__((ext_vector_type(8)));
typedef float    f32x4 __attribute__((ext_vector_type(4)));

union U4H8 { uint4 u; f16x8 h; };

__device__ __forceinline__ unsigned pack_h2(float a, float b) {
    union { _Float16 h[2]; unsigned u; } v;
    v.h[0] = (_Float16)a; v.h[1] = (_Float16)b;
    return v.u;
}
__device__ __forceinline__ float sigmoid_f(float x) {
    return __builtin_amdgcn_rcpf(1.0f + __expf(-x));
}
__device__ __forceinline__ float tanh_f(float x) {
    return 1.0f - 2.0f * __builtin_amdgcn_rcpf(1.0f + __expf(2.0f * x));
}

// ---- weight-value generators (source layouts) ----
// gate order r,z(u),n ; W_ih [600,64], W_hh [600,200]
__device__ __forceinline__ float gru_val(const float* Wih, const float* Whh,
                                         int f, int c, int kl) {
    if (f >= 200) return 0.f;
    if (c < 18) {                       // r (c<9) or u (9<=c<18), full K
        int row = (c < 9) ? f : (200 + f);
        int ks  = (c < 9) ? c : (c - 9);
        int k = ks * 32 + kl;
        if (k < 64)  return Wih[row * 64 + k];
        if (k < 264) return Whh[row * 200 + (k - 64)];
        return 0.f;
    } else if (c < 20) {                // i_n: ks 0..1, k<64 always
        int k = (c - 18) * 32 + kl;
        return Wih[(400 + f) * 64 + k];
    } else {                            // h_n: ks 2..8  ((c-20+2)*32 == (c-18)*32)
        int k = (c - 18) * 32 + kl;
        if (k < 264) return Whh[(400 + f) * 200 + (k - 64)];
        return 0.f;
    }
}
__device__ __forceinline__ float mlp_val(const float* W, int f, int ks, int kl) {
    int k = ks * 32 + kl;
    return (f < 200 && k < 200) ? W[f * 200 + k] : 0.f;
}
__device__ __forceinline__ float ms_val(const float* Wm, const float* Ws,
                                        int n, int ks, int kl) {
    int k = ks * 32 + kl;
    if (k >= 200) return 0.f;
    return (n < 32) ? Wm[n * 200 + k] : Ws[(n - 32) * 200 + k];
}

__global__ void pack_weights(const float* __restrict__ Wih, const float* __restrict__ Whh,
                             const float* __restrict__ W1, const float* __restrict__ W2,
                             const float* __restrict__ Wm, const float* __restrict__ Ws,
                             unsigned* __restrict__ ws)
{
    int i = blockIdx.x * 256 + threadIdx.x;
    if (i >= WS_DW) return;
    float v0 = 0.f, v1 = 0.f;
    if (i < OFF_W1) {                         // GRU region
        int e    = i * 2;                     // f16 element index (e, e+1)
        int tile = e >> 9;                    // 512 f16 per fragment-group
        int r    = e & 511;
        int lane = r >> 3;
        int jx   = r & 7;
        int j = tile / 27, c = tile % 27;
        int n16 = lane & 15, kg = lane >> 4;
        int f = j * 16 + n16;
        v0 = gru_val(Wih, Whh, f, c, kg * 8 + jx);
        v1 = gru_val(Wih, Whh, f, c, kg * 8 + jx + 1);
    } else if (i < OFF_W2) {                  // W1
        int e = (i - OFF_W1) * 2;
        int tile = e >> 9, r = e & 511, lane = r >> 3, jx = r & 7;
        int j = tile / 7, ks = tile % 7;
        int n16 = lane & 15, kg = lane >> 4;
        int f = j * 16 + n16;
        v0 = mlp_val(W1, f, ks, kg * 8 + jx);
        v1 = mlp_val(W1, f, ks, kg * 8 + jx + 1);
    } else if (i < OFF_MS) {                  // W2
        int e = (i - OFF_W2) * 2;
        int tile = e >> 9, r = e & 511, lane = r >> 3, jx = r & 7;
        int j = tile / 7, ks = tile % 7;
        int n16 = lane & 15, kg = lane >> 4;
        int f = j * 16 + n16;
        v0 = mlp_val(W2, f, ks, kg * 8 + jx);
        v1 = mlp_val(W2, f, ks, kg * 8 + jx + 1);
    } else {                                  // MS heads
        int e = (i - OFF_MS) * 2;
        int tile = e >> 9, r = e & 511, lane = r >> 3, jx = r & 7;
        int nt = tile / 7, ks = tile % 7;
        int n16 = lane & 15, kg = lane >> 4;
        int n = nt * 16 + n16;
        v0 = ms_val(Wm, Ws, n, ks, kg * 8 + jx);
        v1 = ms_val(Wm, Ws, n, ks, kg * 8 + jx + 1);
    }
    ws[i] = pack_h2(v0, v1);
}

#define MFMA(a, b, c) __builtin_amdgcn_mfma_f32_16x16x32_f16((a), (b), (c), 0, 0, 0)

__global__ __launch_bounds__(256, 1) void rssm_rollout(
    const float* __restrict__ h0, const float* __restrict__ z0,
    const float* __restrict__ actions, const float* __restrict__ eps,
    const float* __restrict__ b_ih, const float* __restrict__ b_hh,
    const float* __restrict__ b1, const float* __restrict__ b2,
    const float* __restrict__ bm, const float* __restrict__ bs,
    const unsigned* __restrict__ wsu, float* __restrict__ out)
{
    // X rows = batch-in-tile m (16), cols: z 0-31 | a 32-63 | h 64-263 | pad 264-287 (=0)
    __shared__ __align__(16) f16  Xs[16][296];   // stride 592B -> 2-way-free bank pattern
    __shared__ __align__(16) f16  F1s[16][232];
    __shared__ __align__(16) f16  F2s[16][232];
    __shared__ float HF[16][210];                // fp32 h (leak term)
    __shared__ float MSB[16][66];                // mean(0-31) / std(32-63)
    __shared__ float brzL[208], buzL[208], binL[208], bhnL[208], b1L[208], b2L[208], bmsL[64];

    const int t    = threadIdx.x;
    const int w    = t >> 6;
    const int lane = t & 63;
    const int n16  = lane & 15;
    const int kg   = lane >> 4;
    const int b0   = blockIdx.x * BT;

    const uint4* GW  = (const uint4*)(wsu + OFF_GRU);
    const uint4* W1W = (const uint4*)(wsu + OFF_W1);
    const uint4* W2W = (const uint4*)(wsu + OFF_W2);
    const uint4* MSW = (const uint4*)(wsu + OFF_MS);

    // ---- zero LDS (pads must be 0) ----
    {
        unsigned* p;
        p = (unsigned*)&Xs[0][0];  for (int i = t; i < 16 * 296 / 2; i += 256) p[i] = 0u;
        p = (unsigned*)&F1s[0][0]; for (int i = t; i < 16 * 232 / 2; i += 256) p[i] = 0u;
        p = (unsigned*)&F2s[0][0]; for (int i = t; i < 16 * 232 / 2; i += 256) p[i] = 0u;
        float* q = (float*)&HF[0][0];
        for (int i = t; i < 16 * 210; i += 256) q[i] = 0.f;
    }
    if (t < 208) {
        int f = t; bool real = (f < 200);
        brzL[f] = real ? (b_ih[f] + b_hh[f]) : 0.f;
        buzL[f] = real ? (b_ih[200 + f] + b_hh[200 + f]) : 0.f;
        binL[f] = real ? b_ih[400 + f] : 0.f;
        bhnL[f] = real ? b_hh[400 + f] : 0.f;
        b1L[f]  = real ? b1[f] : 0.f;
        b2L[f]  = real ? b2[f] : 0.f;
    }
    if (t < 64) bmsL[t] = (t < 32) ? bm[t] : bs[t - 32];
    __syncthreads();

    // ---- initial state fill ----
    {
        int m = t >> 4, fb = t & 15;
        Xs[m][fb]      = (f16)z0[(b0 + m) * 32 + fb];
        Xs[m][16 + fb] = (f16)z0[(b0 + m) * 32 + 16 + fb];
        Xs[m][32 + fb] = (f16)actions[((b0 + m) * H_STEPS + 0) * 32 + fb];
        Xs[m][48 + fb] = (f16)actions[((b0 + m) * H_STEPS + 0) * 32 + 16 + fb];
        #pragma unroll
        for (int i = 0; i < 13; ++i) {
            int f = fb + 16 * i;
            if (f < 200) {
                float v = h0[(b0 + m) * 200 + f];
                Xs[m][64 + f] = (f16)v;
                HF[m][f] = v;
            }
        }
    }
    __syncthreads();

    for (int step = 0; step < H_STEPS; ++step) {
        const int sp = (step + 1 < H_STEPS) ? step + 1 : step;

        // A-fragments for GRU (shared by all waves): lane holds X[n16][ks*32+kg*8 ..+7]
        f16x8 A9[9];
        #pragma unroll
        for (int ks = 0; ks < 9; ++ks)
            A9[ks] = *(const f16x8*)&Xs[n16][ks * 32 + kg * 8];

        // prefetch eps(cur) / actions(next) — consumed after heads
        const int m_t = t >> 4, fb_t = t & 15;
        float ep0 = eps[((b0 + m_t) * H_STEPS + step) * 32 + fb_t];
        float ep1 = eps[((b0 + m_t) * H_STEPS + step) * 32 + 16 + fb_t];
        float ac0 = actions[((b0 + m_t) * H_STEPS + sp) * 32 + fb_t];
        float ac1 = actions[((b0 + m_t) * H_STEPS + sp) * 32 + 16 + fb_t];
        __syncthreads();   // B2: X free for h' overwrite

        // ---- GRU: wave w owns j = w, w+4, w+8, (w+12) ----
        for (int jj = 0; jj < 4; ++jj) {
            int j = w + 4 * jj;
            if (j < 13) {
                const uint4* tb = GW + (size_t)(j * 27) * 64 + lane;
                U4H8 bfr[27];
                #pragma unroll
                for (int c = 0; c < 27; ++c) bfr[c].u = tb[c * 64];
                f32x4 aR = {0.f,0.f,0.f,0.f}, aU = {0.f,0.f,0.f,0.f};
                f32x4 aI = {0.f,0.f,0.f,0.f}, aH = {0.f,0.f,0.f,0.f};
                #pragma unroll
                for (int ks = 0; ks < 9; ++ks) aR = MFMA(A9[ks], bfr[ks].h, aR);
                #pragma unroll
                for (int ks = 0; ks < 9; ++ks) aU = MFMA(A9[ks], bfr[9 + ks].h, aU);
                #pragma unroll
                for (int ks = 0; ks < 2; ++ks) aI = MFMA(A9[ks], bfr[18 + ks].h, aI);
                #pragma unroll
                for (int ks = 0; ks < 7; ++ks) aH = MFMA(A9[2 + ks], bfr[20 + ks].h, aH);
                const int f = 16 * j + n16;
                const float vbrz = brzL[f], vbuz = buzL[f], vbin = binL[f], vbhn = bhnL[f];
                #pragma unroll
                for (int q = 0; q < 4; ++q) {
                    int m = kg * 4 + q;                 // C/D: row=(lane>>4)*4+reg, col=lane&15
                    float r = sigmoid_f(aR[q] + vbrz);
                    float u = sigmoid_f(aU[q] + vbuz);
                    float n = tanh_f(aI[q] + vbin + r * (aH[q] + vbhn));
                    float ho = HF[m][f];
                    float hnew = (1.0f - u) * n + u * ho;
                    HF[m][f] = hnew;
                    Xs[m][64 + f] = (f16)hnew;
                    if (f < 200)
                        out[((size_t)(b0 + m) * H_STEPS + step) * OUT_FEAT + f] = hnew;
                }
            }
        }
        __syncthreads();   // B3: h' ready in Xs

        // ---- MLP1: F1 = elu(h' @ W1^T + b1), K=224 from X cols 64..287 ----
        {
            f16x8 A7[7];
            #pragma unroll
            for (int ks = 0; ks < 7; ++ks)
                A7[ks] = *(const f16x8*)&Xs[n16][64 + ks * 32 + kg * 8];
            for (int jj = 0; jj < 4; ++jj) {
                int j = w + 4 * jj;
                if (j < 13) {
                    const uint4* tb = W1W + (size_t)(j * 7) * 64 + lane;
                    U4H8 bfr[7];
                    #pragma unroll
                    for (int c = 0; c < 7; ++c) bfr[c].u = tb[c * 64];
                    f32x4 acc = {0.f,0.f,0.f,0.f};
                    #pragma unroll
                    for (int ks = 0; ks < 7; ++ks) acc = MFMA(A7[ks], bfr[ks].h, acc);
                    const int f = 16 * j + n16;
                    const float bb = b1L[f];
                    #pragma unroll
                    for (int q = 0; q < 4; ++q) {
                        float v = acc[q] + bb;
                        v = (v > 0.f) ? v : (__expf(v) - 1.0f);
                        F1s[kg * 4 + q][f] = (f16)v;
                    }
                }
            }
        }
        __syncthreads();   // B4

        // ---- MLP2: F2 = elu(F1 @ W2^T + b2) ----
        {
            f16x8 A7[7];
            #pragma unroll
            for (int ks = 0; ks < 7; ++ks)
                A7[ks] = *(const f16x8*)&F1s[n16][ks * 32 + kg * 8];
            for (int jj = 0; jj < 4; ++jj) {
                int j = w + 4 * jj;
                if (j < 13) {
                    const uint4* tb = W2W + (size_t)(j * 7) * 64 + lane;
                    U4H8 bfr[7];
                    #pragma unroll
                    for (int c = 0; c < 7; ++c) bfr[c].u = tb[c * 64];
                    f32x4 acc = {0.f,0.f,0.f,0.f};
                    #pragma unroll
                    for (int ks = 0; ks < 7; ++ks) acc = MFMA(A7[ks], bfr[ks].h, acc);
                    const int f = 16 * j + n16;
                    const float bb = b2L[f];
                    #pragma unroll
                    for (int q = 0; q < 4; ++q) {
                        float v = acc[q] + bb;
                        v = (v > 0.f) ? v : (__expf(v) - 1.0f);
                        F2s[kg * 4 + q][f] = (f16)v;
                    }
                }
            }
        }
        __syncthreads();   // B5

        // ---- heads: wave w computes n-tile w (mean: tiles 0-1, logstd: 2-3) ----
        {
            f16x8 A7[7];
            #pragma unroll
            for (int ks = 0; ks < 7; ++ks)
                A7[ks] = *(const f16x8*)&F2s[n16][ks * 32 + kg * 8];
            const uint4* tb = MSW + (size_t)(w * 7) * 64 + lane;
            U4H8 bfr[7];
            #pragma unroll
            for (int c = 0; c < 7; ++c) bfr[c].u = tb[c * 64];
            f32x4 acc = {0.f,0.f,0.f,0.f};
            #pragma unroll
            for (int ks = 0; ks < 7; ++ks) acc = MFMA(A7[ks], bfr[ks].h, acc);
            const int n = 16 * w + n16;
            const float bb = bmsL[n];
            #pragma unroll
            for (int q = 0; q < 4; ++q) {
                int m = kg * 4 + q;
                float v = acc[q] + bb;
                size_t ob = ((size_t)(b0 + m) * H_STEPS + step) * OUT_FEAT;
                if (n < 32) {
                    MSB[m][n] = v;
                    out[ob + 232 + n] = v;
                } else {
                    float ls = fminf(fmaxf(v, -10.0f), 2.0f);
                    float sd = __expf(ls);
                    MSB[m][n] = sd;
                    out[ob + 264 + (n - 32)] = sd;
                }
            }
        }
        __syncthreads();   // B6: mean/std ready

        // ---- z = mean + std*eps ; refill X (z, next a) ----
        {
            int m = t >> 4, fb = t & 15;
            float z0v = MSB[m][fb]      + MSB[m][32 + fb] * ep0;
            float z1v = MSB[m][16 + fb] + MSB[m][48 + fb] * ep1;
            size_t ob = ((size_t)(b0 + m) * H_STEPS + step) * OUT_FEAT;
            out[ob + 200 + fb] = z0v;
            out[ob + 216 + fb] = z1v;
            Xs[m][fb]      = (f16)z0v;
            Xs[m][16 + fb] = (f16)z1v;
            Xs[m][32 + fb] = (f16)ac0;
            Xs[m][48 + fb] = (f16)ac1;
        }
        __syncthreads();   // loop-top: X ready
    }
}

extern "C" void kernel_launch(void* const* d_in, const int* in_sizes, int n_in,
                              void* d_out, int out_size, void* d_ws, size_t ws_size,
                              hipStream_t stream) {
    const float* h0      = (const float*)d_in[0];
    const float* z0      = (const float*)d_in[1];
    const float* actions = (const float*)d_in[2];
    const float* eps     = (const float*)d_in[3];
    const float* W_ih    = (const float*)d_in[4];
    const float* b_ih    = (const float*)d_in[5];
    const float* W_hh    = (const float*)d_in[6];
    const float* b_hh    = (const float*)d_in[7];
    const float* W1      = (const float*)d_in[8];
    const float* b1      = (const float*)d_in[9];
    const float* W2      = (const float*)d_in[10];
    const float* b2      = (const float*)d_in[11];
    const float* Wm      = (const float*)d_in[12];
    const float* bm      = (const float*)d_in[13];
    const float* Ws      = (const float*)d_in[14];
    const float* bs      = (const float*)d_in[15];

    unsigned* ws = (unsigned*)d_ws;   // needs >= 574,464 bytes
    float* out = (float*)d_out;

    hipLaunchKernelGGL(pack_weights, dim3(WS_DW / 256), dim3(256), 0, stream,
                       W_ih, W_hh, W1, W2, Wm, Ws, ws);

    hipLaunchKernelGGL(rssm_rollout, dim3(B_TOT / BT), dim3(256), 0, stream,
                       h0, z0, actions, eps, b_ih, b_hh, b1, b2, bm, bs, ws, out);
}

// Round 3
// 631.683 us; speedup vs baseline: 3.4640x; 1.6597x over previous
//
#include <hip/hip_runtime.h>
#include <math.h>

// ---- problem constants ----
#define B_TOT    2048
#define H_STEPS  64
#define OUT_FEAT 296
#define BT       16           // batch rows per block -> grid 128
#define NTHR     512          // 8 waves -> 2 waves/SIMD co-resident

// ---- workspace layout (dword offsets), f16 MFMA B-fragments ----
// GRU: 13 j-tiles x 27 frag-groups (r:ks0-8, u:ks0-8, in:ks0-1, hn:ks2-8), 64 lanes x 16B
// W1 : 13 x 7, W2: 13 x 7, MS: 4 x 7
#define OFF_GRU 0
#define OFF_W1  89856        // 13*27*1024B /4
#define OFF_W2  113152       // +13*7*1024B/4
#define OFF_MS  136448
#define WS_DW   143616       // 574,464 bytes total

typedef _Float16 f16;
typedef _Float16 f16x8 __attribute__((ext_vector_type(8)));
typedef float    f32x4 __attribute__((ext_vector_type(4)));

union U4H8 { uint4 u; f16x8 h; };

__device__ __forceinline__ unsigned pack_h2(float a, float b) {
    union { _Float16 h[2]; unsigned u; } v;
    v.h[0] = (_Float16)a; v.h[1] = (_Float16)b;
    return v.u;
}
__device__ __forceinline__ float sigmoid_f(float x) {
    return __builtin_amdgcn_rcpf(1.0f + __expf(-x));
}
__device__ __forceinline__ float tanh_f(float x) {
    return 1.0f - 2.0f * __builtin_amdgcn_rcpf(1.0f + __expf(2.0f * x));
}

// ---- weight-value generators (source layouts) ----
// gate order r,z(u),n ; W_ih [600,64], W_hh [600,200]
__device__ __forceinline__ float gru_val(const float* Wih, const float* Whh,
                                         int f, int c, int kl) {
    if (f >= 200) return 0.f;
    if (c < 18) {                       // r (c<9) or u (9<=c<18), full K
        int row = (c < 9) ? f : (200 + f);
        int ks  = (c < 9) ? c : (c - 9);
        int k = ks * 32 + kl;
        if (k < 64)  return Wih[row * 64 + k];
        if (k < 264) return Whh[row * 200 + (k - 64)];
        return 0.f;
    } else if (c < 20) {                // i_n: ks 0..1, k<64 always
        int k = (c - 18) * 32 + kl;
        return Wih[(400 + f) * 64 + k];
    } else {                            // h_n: ks 2..8  ((c-20+2)*32 == (c-18)*32)
        int k = (c - 18) * 32 + kl;
        if (k < 264) return Whh[(400 + f) * 200 + (k - 64)];
        return 0.f;
    }
}
__device__ __forceinline__ float mlp_val(const float* W, int f, int ks, int kl) {
    int k = ks * 32 + kl;
    return (f < 200 && k < 200) ? W[f * 200 + k] : 0.f;
}
__device__ __forceinline__ float ms_val(const float* Wm, const float* Ws,
                                        int n, int ks, int kl) {
    int k = ks * 32 + kl;
    if (k >= 200) return 0.f;
    return (n < 32) ? Wm[n * 200 + k] : Ws[(n - 32) * 200 + k];
}

__global__ void pack_weights(const float* __restrict__ Wih, const float* __restrict__ Whh,
                             const float* __restrict__ W1, const float* __restrict__ W2,
                             const float* __restrict__ Wm, const float* __restrict__ Ws,
                             unsigned* __restrict__ ws)
{
    int i = blockIdx.x * 256 + threadIdx.x;
    if (i >= WS_DW) return;
    float v0 = 0.f, v1 = 0.f;
    if (i < OFF_W1) {                         // GRU region
        int e    = i * 2;                     // f16 element index (e, e+1)
        int tile = e >> 9;                    // 512 f16 per fragment-group
        int r    = e & 511;
        int lane = r >> 3;
        int jx   = r & 7;
        int j = tile / 27, c = tile % 27;
        int n16 = lane & 15, kg = lane >> 4;
        int f = j * 16 + n16;
        v0 = gru_val(Wih, Whh, f, c, kg * 8 + jx);
        v1 = gru_val(Wih, Whh, f, c, kg * 8 + jx + 1);
    } else if (i < OFF_W2) {                  // W1
        int e = (i - OFF_W1) * 2;
        int tile = e >> 9, r = e & 511, lane = r >> 3, jx = r & 7;
        int j = tile / 7, ks = tile % 7;
        int n16 = lane & 15, kg = lane >> 4;
        int f = j * 16 + n16;
        v0 = mlp_val(W1, f, ks, kg * 8 + jx);
        v1 = mlp_val(W1, f, ks, kg * 8 + jx + 1);
    } else if (i < OFF_MS) {                  // W2
        int e = (i - OFF_W2) * 2;
        int tile = e >> 9, r = e & 511, lane = r >> 3, jx = r & 7;
        int j = tile / 7, ks = tile % 7;
        int n16 = lane & 15, kg = lane >> 4;
        int f = j * 16 + n16;
        v0 = mlp_val(W2, f, ks, kg * 8 + jx);
        v1 = mlp_val(W2, f, ks, kg * 8 + jx + 1);
    } else {                                  // MS heads
        int e = (i - OFF_MS) * 2;
        int tile = e >> 9, r = e & 511, lane = r >> 3, jx = r & 7;
        int nt = tile / 7, ks = tile % 7;
        int n16 = lane & 15, kg = lane >> 4;
        int n = nt * 16 + n16;
        v0 = ms_val(Wm, Ws, n, ks, kg * 8 + jx);
        v1 = ms_val(Wm, Ws, n, ks, kg * 8 + jx + 1);
    }
    ws[i] = pack_h2(v0, v1);
}

#define MFMA(a, b, c) __builtin_amdgcn_mfma_f32_16x16x32_f16((a), (b), (c), 0, 0, 0)

__global__ __launch_bounds__(NTHR, 1) void rssm_rollout(
    const float* __restrict__ h0, const float* __restrict__ z0,
    const float* __restrict__ actions, const float* __restrict__ eps,
    const float* __restrict__ b_ih, const float* __restrict__ b_hh,
    const float* __restrict__ b1, const float* __restrict__ b2,
    const float* __restrict__ bm, const float* __restrict__ bs,
    const unsigned* __restrict__ wsu, float* __restrict__ out)
{
    // X rows = batch-in-tile m (16), cols: z 0-31 | a 32-63 | h 64-263 | pad 264-287 (=0)
    __shared__ __align__(16) f16  Xs[16][296];   // stride 592B
    __shared__ __align__(16) f16  F1s[16][232];
    __shared__ __align__(16) f16  F2s[16][232];
    __shared__ float HF[16][210];                // fp32 h (leak term)
    __shared__ float MSB[16][66];                // mean(0-31) / std(32-63)
    __shared__ float brzL[208], buzL[208], binL[208], bhnL[208], b1L[208], b2L[208], bmsL[64];

    const int t    = threadIdx.x;
    const int w    = t >> 6;                     // 0..7
    const int lane = t & 63;
    const int n16  = lane & 15;
    const int kg   = lane >> 4;
    const int b0   = blockIdx.x * BT;

    const uint4* GW  = (const uint4*)(wsu + OFF_GRU);
    const uint4* W1W = (const uint4*)(wsu + OFF_W1);
    const uint4* W2W = (const uint4*)(wsu + OFF_W2);
    const uint4* MSW = (const uint4*)(wsu + OFF_MS);

    // ---- zero LDS (pads must be 0) ----
    {
        unsigned* p;
        p = (unsigned*)&Xs[0][0];  for (int i = t; i < 16 * 296 / 2; i += NTHR) p[i] = 0u;
        p = (unsigned*)&F1s[0][0]; for (int i = t; i < 16 * 232 / 2; i += NTHR) p[i] = 0u;
        p = (unsigned*)&F2s[0][0]; for (int i = t; i < 16 * 232 / 2; i += NTHR) p[i] = 0u;
        float* q = (float*)&HF[0][0];
        for (int i = t; i < 16 * 210; i += NTHR) q[i] = 0.f;
    }
    if (t < 208) {
        int f = t; bool real = (f < 200);
        brzL[f] = real ? (b_ih[f] + b_hh[f]) : 0.f;
        buzL[f] = real ? (b_ih[200 + f] + b_hh[200 + f]) : 0.f;
        binL[f] = real ? b_ih[400 + f] : 0.f;
        bhnL[f] = real ? b_hh[400 + f] : 0.f;
        b1L[f]  = real ? b1[f] : 0.f;
        b2L[f]  = real ? b2[f] : 0.f;
    }
    if (t < 64) bmsL[t] = (t < 32) ? bm[t] : bs[t - 32];
    __syncthreads();

    // ---- initial state fill ----
    if (t < 256) {
        int m = t >> 4, fb = t & 15;
        Xs[m][fb]      = (f16)z0[(b0 + m) * 32 + fb];
        Xs[m][16 + fb] = (f16)z0[(b0 + m) * 32 + 16 + fb];
        Xs[m][32 + fb] = (f16)actions[((b0 + m) * H_STEPS + 0) * 32 + fb];
        Xs[m][48 + fb] = (f16)actions[((b0 + m) * H_STEPS + 0) * 32 + 16 + fb];
        #pragma unroll
        for (int i = 0; i < 13; ++i) {
            int f = fb + 16 * i;
            if (f < 200) {
                float v = h0[(b0 + m) * 200 + f];
                Xs[m][64 + f] = (f16)v;
                HF[m][f] = v;
            }
        }
    }
    __syncthreads();

    for (int step = 0; step < H_STEPS; ++step) {
        const int sp = (step + 1 < H_STEPS) ? step + 1 : step;

        // A-fragments for GRU (per wave): lane holds X[n16][ks*32+kg*8 ..+7]
        f16x8 A9[9];
        #pragma unroll
        for (int ks = 0; ks < 9; ++ks)
            A9[ks] = *(const f16x8*)&Xs[n16][ks * 32 + kg * 8];

        // prefetch eps(cur) / actions(next) — consumed after heads (threads 0-255)
        float ep0 = 0.f, ep1 = 0.f, ac0 = 0.f, ac1 = 0.f;
        if (t < 256) {
            int m_t = t >> 4, fb_t = t & 15;
            ep0 = eps[((b0 + m_t) * H_STEPS + step) * 32 + fb_t];
            ep1 = eps[((b0 + m_t) * H_STEPS + step) * 32 + 16 + fb_t];
            ac0 = actions[((b0 + m_t) * H_STEPS + sp) * 32 + fb_t];
            ac1 = actions[((b0 + m_t) * H_STEPS + sp) * 32 + 16 + fb_t];
        }
        __syncthreads();   // B2: A9 read everywhere; X free for h' overwrite

        // ---- GRU: wave w owns j = w, w+8 ----
        for (int j = w; j < 13; j += 8) {
            const uint4* tb = GW + (size_t)(j * 27) * 64 + lane;
            U4H8 bfr[27];
            #pragma unroll
            for (int c = 0; c < 27; ++c) bfr[c].u = tb[c * 64];
            f32x4 aR = {0.f,0.f,0.f,0.f}, aU = {0.f,0.f,0.f,0.f};
            f32x4 aI = {0.f,0.f,0.f,0.f}, aH = {0.f,0.f,0.f,0.f};
            #pragma unroll
            for (int ks = 0; ks < 9; ++ks) aR = MFMA(A9[ks], bfr[ks].h, aR);
            #pragma unroll
            for (int ks = 0; ks < 9; ++ks) aU = MFMA(A9[ks], bfr[9 + ks].h, aU);
            #pragma unroll
            for (int ks = 0; ks < 2; ++ks) aI = MFMA(A9[ks], bfr[18 + ks].h, aI);
            #pragma unroll
            for (int ks = 0; ks < 7; ++ks) aH = MFMA(A9[2 + ks], bfr[20 + ks].h, aH);
            const int f = 16 * j + n16;
            const float vbrz = brzL[f], vbuz = buzL[f], vbin = binL[f], vbhn = bhnL[f];
            #pragma unroll
            for (int q = 0; q < 4; ++q) {
                int m = kg * 4 + q;                 // C/D: row=(lane>>4)*4+reg, col=lane&15
                float r = sigmoid_f(aR[q] + vbrz);
                float u = sigmoid_f(aU[q] + vbuz);
                float n = tanh_f(aI[q] + vbin + r * (aH[q] + vbhn));
                float ho = HF[m][f];
                float hnew = (1.0f - u) * n + u * ho;
                HF[m][f] = hnew;
                Xs[m][64 + f] = (f16)hnew;
                if (f < 200)
                    out[((size_t)(b0 + m) * H_STEPS + step) * OUT_FEAT + f] = hnew;
            }
        }
        __syncthreads();   // B3: h' ready in Xs

        // ---- MLP1: F1 = elu(h' @ W1^T + b1), K=224 from X cols 64..287 ----
        {
            f16x8 A7[7];
            #pragma unroll
            for (int ks = 0; ks < 7; ++ks)
                A7[ks] = *(const f16x8*)&Xs[n16][64 + ks * 32 + kg * 8];
            for (int j = w; j < 13; j += 8) {
                const uint4* tb = W1W + (size_t)(j * 7) * 64 + lane;
                U4H8 bfr[7];
                #pragma unroll
                for (int c = 0; c < 7; ++c) bfr[c].u = tb[c * 64];
                f32x4 acc = {0.f,0.f,0.f,0.f};
                #pragma unroll
                for (int ks = 0; ks < 7; ++ks) acc = MFMA(A7[ks], bfr[ks].h, acc);
                const int f = 16 * j + n16;
                const float bb = b1L[f];
                #pragma unroll
                for (int q = 0; q < 4; ++q) {
                    float v = acc[q] + bb;
                    v = (v > 0.f) ? v : (__expf(v) - 1.0f);
                    F1s[kg * 4 + q][f] = (f16)v;
                }
            }
        }
        __syncthreads();   // B4

        // ---- MLP2: F2 = elu(F1 @ W2^T + b2) ----
        {
            f16x8 A7[7];
            #pragma unroll
            for (int ks = 0; ks < 7; ++ks)
                A7[ks] = *(const f16x8*)&F1s[n16][ks * 32 + kg * 8];
            for (int j = w; j < 13; j += 8) {
                const uint4* tb = W2W + (size_t)(j * 7) * 64 + lane;
                U4H8 bfr[7];
                #pragma unroll
                for (int c = 0; c < 7; ++c) bfr[c].u = tb[c * 64];
                f32x4 acc = {0.f,0.f,0.f,0.f};
                #pragma unroll
                for (int ks = 0; ks < 7; ++ks) acc = MFMA(A7[ks], bfr[ks].h, acc);
                const int f = 16 * j + n16;
                const float bb = b2L[f];
                #pragma unroll
                for (int q = 0; q < 4; ++q) {
                    float v = acc[q] + bb;
                    v = (v > 0.f) ? v : (__expf(v) - 1.0f);
                    F2s[kg * 4 + q][f] = (f16)v;
                }
            }
        }
        __syncthreads();   // B5

        // ---- heads: wave w<4 computes n-tile w (mean: tiles 0-1, logstd: 2-3) ----
        if (w < 4) {
            f16x8 A7[7];
            #pragma unroll
            for (int ks = 0; ks < 7; ++ks)
                A7[ks] = *(const f16x8*)&F2s[n16][ks * 32 + kg * 8];
            const uint4* tb = MSW + (size_t)(w * 7) * 64 + lane;
            U4H8 bfr[7];
            #pragma unroll
            for (int c = 0; c < 7; ++c) bfr[c].u = tb[c * 64];
            f32x4 acc = {0.f,0.f,0.f,0.f};
            #pragma unroll
            for (int ks = 0; ks < 7; ++ks) acc = MFMA(A7[ks], bfr[ks].h, acc);
            const int n = 16 * w + n16;
            const float bb = bmsL[n];
            #pragma unroll
            for (int q = 0; q < 4; ++q) {
                int m = kg * 4 + q;
                float v = acc[q] + bb;
                size_t ob = ((size_t)(b0 + m) * H_STEPS + step) * OUT_FEAT;
                if (n < 32) {
                    MSB[m][n] = v;
                    out[ob + 232 + n] = v;
                } else {
                    float ls = fminf(fmaxf(v, -10.0f), 2.0f);
                    float sd = __expf(ls);
                    MSB[m][n] = sd;
                    out[ob + 264 + (n - 32)] = sd;
                }
            }
        }
        __syncthreads();   // B6: mean/std ready

        // ---- z = mean + std*eps ; refill X (z, next a) ----
        if (t < 256) {
            int m = t >> 4, fb = t & 15;
            float z0v = MSB[m][fb]      + MSB[m][32 + fb] * ep0;
            float z1v = MSB[m][16 + fb] + MSB[m][48 + fb] * ep1;
            size_t ob = ((size_t)(b0 + m) * H_STEPS + step) * OUT_FEAT;
            out[ob + 200 + fb] = z0v;
            out[ob + 216 + fb] = z1v;
            Xs[m][fb]      = (f16)z0v;
            Xs[m][16 + fb] = (f16)z1v;
            Xs[m][32 + fb] = (f16)ac0;
            Xs[m][48 + fb] = (f16)ac1;
        }
        __syncthreads();   // loop-top: X ready
    }
}

extern "C" void kernel_launch(void* const* d_in, const int* in_sizes, int n_in,
                              void* d_out, int out_size, void* d_ws, size_t ws_size,
                              hipStream_t stream) {
    const float* h0      = (const float*)d_in[0];
    const float* z0      = (const float*)d_in[1];
    const float* actions = (const float*)d_in[2];
    const float* eps     = (const float*)d_in[3];
    const float* W_ih    = (const float*)d_in[4];
    const float* b_ih    = (const float*)d_in[5];
    const float* W_hh    = (const float*)d_in[6];
    const float* b_hh    = (const float*)d_in[7];
    const float* W1      = (const float*)d_in[8];
    const float* b1      = (const float*)d_in[9];
    const float* W2      = (const float*)d_in[10];
    const float* b2      = (const float*)d_in[11];
    const float* Wm      = (const float*)d_in[12];
    const float* bm      = (const float*)d_in[13];
    const float* Ws      = (const float*)d_in[14];
    const float* bs      = (const float*)d_in[15];

    unsigned* ws = (unsigned*)d_ws;   // needs >= 574,464 bytes
    float* out = (float*)d_out;

    hipLaunchKernelGGL(pack_weights, dim3(WS_DW / 256), dim3(256), 0, stream,
                       W_ih, W_hh, W1, W2, Wm, Ws, ws);

    hipLaunchKernelGGL(rssm_rollout, dim3(B_TOT / BT), dim3(NTHR), 0, stream,
                       h0, z0, actions, eps, b_ih, b_hh, b1, b2, bm, bs, ws, out);
}